// Round 2
// baseline (203.873 us; speedup 1.0000x reference)
//
#include <hip/hip_runtime.h>
#include <hip/hip_bf16.h>
#include <stdint.h>

#define S_LEN 1024
#define HDIM  1024
#define NHEADS 16
#define HEAD_D 64
#define KSEL  512
#define BATCH 8

typedef unsigned short ushort_t;
typedef __attribute__((ext_vector_type(8))) __bf16 bf16x8;
typedef __attribute__((ext_vector_type(4))) float  f32x4;

typedef const __attribute__((address_space(1))) void cg_void;
typedef __attribute__((address_space(3))) void lds_void;

__device__ __forceinline__ void gl_lds16(const void* g, void* l) {
    __builtin_amdgcn_global_load_lds((cg_void*)g, (lds_void*)l, 16, 0, 0);
}

// round-to-nearest-even f32 -> bf16 (finite inputs only)
__device__ __forceinline__ ushort_t f2bf(float f) {
    union { float f; unsigned int i; } x; x.f = f;
    unsigned int r = (x.i + 0x7fffu + ((x.i >> 16) & 1u)) >> 16;
    return (ushort_t)r;
}

// ---------------- kernel 0: prep = cvt(hidden,Wq,Wk,Wv) + compact -----------
// Writes pos[b][s] = slot (<512) or -1 : inverse permutation for the Q scatter
// epilogue of gemm8 (Q is now computed densely over all 8192 rows).
__global__ __launch_bounds__(1024) void prep_kernel(
    const float* __restrict__ hidden, const float* __restrict__ wq,
    const float* __restrict__ wk, const float* __restrict__ wv,
    const int* __restrict__ remain,
    ushort_t* __restrict__ hbf, ushort_t* __restrict__ wqb,
    ushort_t* __restrict__ wkb, ushort_t* __restrict__ wvb,
    short* __restrict__ pos, int* __restrict__ valid) {
    __shared__ int wsum[16];
    __shared__ int woff[17];
    int blk = blockIdx.x;
    if (blk < 2816) {
        const float* s; ushort_t* d; int base;
        if (blk < 2048)      { s = hidden; d = hbf; base = blk; }
        else if (blk < 2304) { s = wq; d = wqb; base = blk - 2048; }
        else if (blk < 2560) { s = wk; d = wkb; base = blk - 2304; }
        else                 { s = wv; d = wvb; base = blk - 2560; }
        int i = base * 1024 + threadIdx.x;
        float4 v = ((const float4*)s)[i];
        ushort4 o;
        o.x = f2bf(v.x); o.y = f2bf(v.y); o.z = f2bf(v.z); o.w = f2bf(v.w);
        ((ushort4*)d)[i] = o;
    } else {
        int b = blk - 2816, t = threadIdx.x;
        int r = remain[b * S_LEN + t];
        unsigned long long m = __ballot(r != 0);
        int lane = t & 63, w = t >> 6;
        int pre = __popcll(m & ((1ull << lane) - 1ull));
        if (lane == 0) wsum[w] = __popcll(m);
        __syncthreads();
        if (t == 0) { int a = 0; for (int i = 0; i < 16; i++) { woff[i] = a; a += wsum[i]; } woff[16] = a; }
        __syncthreads();
        int tot = woff[16];
        int onesBefore = woff[w] + pre;
        int slot = r ? onesBefore : (tot + (t - onesBefore));
        pos[b * S_LEN + t] = (short)((slot < KSEL) ? slot : -1);
        if (slot < KSEL) valid[b * KSEL + slot] = r;
    }
}

// ---------------- kernel 1: unified projection GEMM, 256^2 8-phase ----------
// C[8192][3072] = hbf @ [Wk;Wv;Wq]^T.  384 blocks x 512 thr (8 waves, 2Mx4N),
// BK=64, LDS 128KiB (2 dbuf x 2 row-half x 128x64 x {A,B} bf16).
// 8-phase/2-Ktile schedule (T3+T4): per phase {ds_read frags | stage 1 half-
// tile | barrier | 16 MFMA (setprio, T5) | barrier}; counted vmcnt(4) ONLY at
// phase 4 (never 0 until tail).  Race-freedom by liveness: B(t) is consumed
// entirely in phase 1 -> B(t+2) staged phases 2/3 into the freed region;
// A(t) is consumed across phases 1-4 -> A(t+1) staged phase 1 into the other
// buffer.  Raw asm s_barrier (memory clobber) avoids the __syncthreads
// vmcnt(0) drain; sched_barrier(0) pins MFMA clusters before trailing BAR.
// LDS swizzle (G4/T2, both-sides): 16B chunk ^= (row&7) on the pre-swizzled
// GLOBAL source (gl_lds writes linearly) and on the ds_read address.
// Epilogues by n-range: K store | V 2-pass LDS transpose | Q scatter via pos.
#define QSCALE 0.1803368801111244f
#define LT_PITCH 264
#define BAR() __asm__ volatile("s_barrier" ::: "memory")
#define VMCNT(n) __asm__ volatile("s_waitcnt vmcnt(" #n ")" ::: "memory")

#define GPHASE(mt0, ...) { \
    bf16x8 Af0, Af1, Af2, Af3; \
    { const ushort_t* ap = &pool[Ab + (mt0) * 1024 + aRow]; \
      Af0 = *(const bf16x8*)(ap + ksw0); \
      Af1 = *(const bf16x8*)(ap + ksw1); \
      Af2 = *(const bf16x8*)(ap + 1024 + ksw0); \
      Af3 = *(const bf16x8*)(ap + 1024 + ksw1); } \
    __VA_ARGS__; \
    BAR(); \
    __builtin_amdgcn_s_setprio(1); \
    _Pragma("unroll") for (int nt = 0; nt < 4; nt++) \
        acc[mt0][nt]   = __builtin_amdgcn_mfma_f32_16x16x32_bf16(Af0, Bf[nt][0], acc[mt0][nt], 0, 0, 0); \
    _Pragma("unroll") for (int nt = 0; nt < 4; nt++) \
        acc[mt0+1][nt] = __builtin_amdgcn_mfma_f32_16x16x32_bf16(Af2, Bf[nt][0], acc[mt0+1][nt], 0, 0, 0); \
    _Pragma("unroll") for (int nt = 0; nt < 4; nt++) \
        acc[mt0][nt]   = __builtin_amdgcn_mfma_f32_16x16x32_bf16(Af1, Bf[nt][1], acc[mt0][nt], 0, 0, 0); \
    _Pragma("unroll") for (int nt = 0; nt < 4; nt++) \
        acc[mt0+1][nt] = __builtin_amdgcn_mfma_f32_16x16x32_bf16(Af3, Bf[nt][1], acc[mt0+1][nt], 0, 0, 0); \
    __builtin_amdgcn_s_setprio(0); \
    __builtin_amdgcn_sched_barrier(0); \
    BAR(); }

__global__ __launch_bounds__(512, 2) void gemm8(
    const ushort_t* __restrict__ hbf, const ushort_t* __restrict__ wkvq,
    const float* __restrict__ bk, const float* __restrict__ bv,
    const float* __restrict__ bq,
    const short* __restrict__ pos, const int* __restrict__ valid,
    ushort_t* __restrict__ kp, ushort_t* __restrict__ vt, ushort_t* __restrict__ qp) {
    __shared__ __align__(16) ushort_t pool[65536];   // 128 KiB
    const int i = blockIdx.x;
    const int swz = (i & 7) * 48 + (i >> 3);         // 384 = 8*48, bijective
    const int bmI = swz / 12, bnI = swz % 12;        // A-panel locality per XCD
    const int bm = bmI * 256;
    const int bn = bnI * 256;

    const int tid = threadIdx.x;
    const int lane = tid & 63;
    const int w = tid >> 6;
    const int quad = lane >> 4;
    const int cl = lane & 15;
    const int wr = w >> 2;                 // 0..1: row half (128 rows)
    const int wc = w & 3;                  // 0..3: col quarter (64 cols)

    // staging map: chunk c = issue*512+tid; row = c>>3, src col-chunk ^= row&7
    const int r0 = tid >> 3;                              // 0..63
    const int csw = ((tid & 7) ^ (r0 & 7)) * 8;           // elems
    const ushort_t* aSrc = hbf  + (bm + r0) * 1024 + csw;
    const ushort_t* bSrc = wkvq + (bn + r0) * 1024 + csw;

    // fragment-read constants (read-side of the same involution)
    const int aRow = cl * 64;
    const int ksw0 = (quad ^ (cl & 7)) * 8;
    const int ksw1 = ksw0 ^ 32;
    const int BbW = 32768 + (wc & 1) * 4096;
    const int BhT = wc >> 1;

    auto stageA = [&](int kt, int half) {
        const ushort_t* s = aSrc + half * 131072 + kt * 64;
        ushort_t* d = &pool[((kt & 1) * 2 + half) * 8192 + tid * 8];
        gl_lds16(s, d);
        gl_lds16(s + 65536, d + 4096);
    };
    auto stageB = [&](int kt, int half) {
        const ushort_t* s = bSrc + half * 131072 + kt * 64;
        ushort_t* d = &pool[32768 + ((kt & 1) * 2 + half) * 8192 + tid * 8];
        gl_lds16(s, d);
        gl_lds16(s + 65536, d + 4096);
    };

    f32x4 acc[8][4] = {};

    // prologue: A(0),B(0) then B(1); vmcnt(4) leaves only B(1) in flight
    stageA(0, 0); stageA(0, 1);
    stageB(0, 0); stageB(0, 1);
    stageB(1, 0); stageB(1, 1);
    VMCNT(4);
    BAR();

    for (int u = 0; u < 16; ++u) {
        const int buf = u & 1;
        const int Ab = (buf * 2 + wr) * 8192;
        const int Bb = BbW + (buf * 2 + BhT) * 8192;

        bf16x8 Bf[4][2];
#pragma unroll
        for (int nt = 0; nt < 4; nt++) {
            const ushort_t* bp = &pool[Bb + nt * 1024 + aRow];
            Bf[nt][0] = *(const bf16x8*)(bp + ksw0);
            Bf[nt][1] = *(const bf16x8*)(bp + ksw1);
        }
        GPHASE(0, { if (u < 15) { stageA(u + 1, 0); stageA(u + 1, 1); } })
        GPHASE(2, { if (u < 14) stageB(u + 2, 0); })
        GPHASE(4, { if (u < 14) stageB(u + 2, 1); })
        GPHASE(6, { if (u < 14) { VMCNT(4); } else { VMCNT(0); } })
    }

    // ---------------- epilogues --------------------------------------------
    const int row0 = bm + wr * 128;
    const int colW = wc * 64;
    if (bnI < 4) {
        // K: kp[row][col] = acc + bk
        const int cb = bn + colW;
#pragma unroll
        for (int nt = 0; nt < 4; nt++) {
            int col = cb + nt * 16 + cl;
            float bb = bk[col];
#pragma unroll
            for (int mt = 0; mt < 8; mt++) {
                int rw = row0 + mt * 16 + quad * 4;
#pragma unroll
                for (int r = 0; r < 4; r++)
                    kp[(rw + r) * 1024 + col] = f2bf(acc[mt][nt][r] + bb);
            }
        }
    } else if (bnI < 8) {
        // V: 2-pass (128 cols) LDS transpose -> coalesced V^T store
        const int vcb = bn - 1024;
        const int b_ = bm >> 10;
        const int s0 = bm & 1023;
#pragma unroll
        for (int p2 = 0; p2 < 2; p2++) {
            if ((wc >> 1) == p2) {
#pragma unroll
                for (int nt = 0; nt < 4; nt++) {
                    int cloc = (wc & 1) * 64 + nt * 16 + cl;   // 0..127
                    float bb = bv[vcb + p2 * 128 + cloc];
#pragma unroll
                    for (int mt = 0; mt < 8; mt++) {
                        int rr = wr * 128 + mt * 16 + quad * 4;
#pragma unroll
                        for (int r = 0; r < 4; r++)
                            pool[cloc * LT_PITCH + rr + r] = f2bf(acc[mt][nt][r] + bb);
                    }
                }
            }
            __syncthreads();
            {
                int col = tid >> 2;            // 0..127
                int sq = tid & 3;
                int gb = ((b_ << 10) + vcb + p2 * 128 + col) * 1024 + s0;
                const ushort_t* src = &pool[col * LT_PITCH];
#pragma unroll
                for (int j = 0; j < 8; j++) {
                    int ch = (sq + 4 * j) * 8;   // bank-spread chunk order
                    *(bf16x8*)(vt + gb + ch) = *(const bf16x8*)(src + ch);
                }
            }
            __syncthreads();
        }
    } else {
        // Q: scatter rows through pos[], mask by valid, add bias, pre-scale
        const int qcb = bn - 2048 + colW;
        float bqv[4];
#pragma unroll
        for (int nt = 0; nt < 4; nt++) bqv[nt] = bq[qcb + nt * 16 + cl];
#pragma unroll
        for (int mt = 0; mt < 8; mt++) {
#pragma unroll
            for (int r = 0; r < 4; r++) {
                int row = row0 + mt * 16 + quad * 4 + r;
                int p = pos[row];
                if (p >= 0) {
                    float vm = (float)valid[((row >> 10) << 9) + p];
                    int ob = ((row >> 10) * 512 + p) * 1024 + qcb;
#pragma unroll
                    for (int nt = 0; nt < 4; nt++)
                        qp[ob + nt * 16 + cl] = f2bf((acc[mt][nt][r] * vm + bqv[nt]) * QSCALE);
                }
            }
        }
    }
}

// ---------------- kernel 2: flash attention, 32 q-rows per wave -------------
// (unchanged from R1: passed, XOR bank swizzles on K/V tiles)
#define P_PITCH 72
__global__ __launch_bounds__(256, 2) void attn_kernel(
    const ushort_t* __restrict__ qp, const ushort_t* __restrict__ kp,
    const ushort_t* __restrict__ vt, const float* __restrict__ mask,
    float* __restrict__ out) {
    __shared__ __align__(16) ushort_t ks[2][4096];
    __shared__ __align__(16) ushort_t vs[2][4096];
    __shared__ __align__(16) ushort_t ps[4][32 * P_PITCH];
    const int tid = threadIdx.x;
    const int lane = tid & 63;
    const int w = tid >> 6;
    const int quad = lane >> 4;
    const int cl = lane & 15;
    const int qt = blockIdx.x, h = blockIdx.y, b = blockIdx.z;

    const int srow = tid >> 2;
    const int fsa = ((tid >> 2) & 3) ^ ((tid >> 4) & 3);
    const int sc8 = ((tid & 3) ^ fsa) * 8;
    const int lds_off = tid * 8;
    const int fr = (cl & 3) ^ ((cl >> 2) & 3);
    const int qo = (quad ^ fr) * 8;

    const long kbase = (long)b * S_LEN;
    const long vbase = (long)b * 1024 + h * HEAD_D;

    const long qrow0 = (long)b * KSEL + qt * 128 + w * 32;
    bf16x8 aq[2][2];
#pragma unroll
    for (int mt = 0; mt < 2; mt++)
#pragma unroll
        for (int kk = 0; kk < 2; kk++)
            aq[mt][kk] = *(const bf16x8*)(qp + (qrow0 + mt * 16 + cl) * HDIM + h * HEAD_D + kk * 32 + quad * 8);

    f32x4 O[2][4] = {};
    float l_r[2][4] = {};

#pragma unroll
    for (int j = 0; j < 2; j++) {
        gl_lds16(kp + (kbase + srow) * (long)HDIM + h * HEAD_D + j * 32 + sc8, &ks[0][j * 2048 + lds_off]);
        gl_lds16(vt + (vbase + srow) * (long)S_LEN + j * 32 + sc8, &vs[0][j * 2048 + lds_off]);
    }

    for (int c = 0; c < S_LEN / 64; c++) {
        __asm__ volatile("s_waitcnt vmcnt(0)" ::: "memory");
        __syncthreads();
        if (c + 1 < S_LEN / 64) {
            int nb = (c + 1) & 1;
#pragma unroll
            for (int j = 0; j < 2; j++) {
                gl_lds16(kp + (kbase + (c + 1) * 64 + srow) * (long)HDIM + h * HEAD_D + j * 32 + sc8,
                         &ks[nb][j * 2048 + lds_off]);
                gl_lds16(vt + (vbase + srow) * (long)S_LEN + (c + 1) * 64 + j * 32 + sc8,
                         &vs[nb][j * 2048 + lds_off]);
            }
        }
        const ushort_t* kbuf = ks[c & 1];
        const ushort_t* vbuf = vs[c & 1];

        f32x4 sc[2][4] = {};
#pragma unroll
        for (int kk = 0; kk < 2; kk++)
#pragma unroll
            for (int nt = 0; nt < 4; nt++) {
                bf16x8 bk8 = *(const bf16x8*)&kbuf[kk * 2048 + (nt * 16 + cl) * 32 + qo];
#pragma unroll
                for (int mt = 0; mt < 2; mt++)
                    sc[mt][nt] = __builtin_amdgcn_mfma_f32_16x16x32_bf16(aq[mt][kk], bk8, sc[mt][nt], 0, 0, 0);
            }

#pragma unroll
        for (int nt = 0; nt < 4; nt++) {
            float mv = mask[b * S_LEN + c * 64 + nt * 16 + cl] * 1.44269504f;
#pragma unroll
            for (int mt = 0; mt < 2; mt++)
#pragma unroll
                for (int r = 0; r < 4; r++) {
                    float p_ = __builtin_amdgcn_exp2f(sc[mt][nt][r] + mv);
                    sc[mt][nt][r] = p_;
                    l_r[mt][r] += p_;
                }
        }

#pragma unroll
        for (int mt = 0; mt < 2; mt++)
#pragma unroll
            for (int nt = 0; nt < 4; nt++)
#pragma unroll
                for (int r = 0; r < 4; r++)
                    ps[w][(mt * 16 + quad * 4 + r) * P_PITCH + nt * 16 + cl] = f2bf(sc[mt][nt][r]);

        __asm__ volatile("s_waitcnt lgkmcnt(0)" ::: "memory");

#pragma unroll
        for (int kk = 0; kk < 2; kk++) {
            bf16x8 ap[2];
#pragma unroll
            for (int mt = 0; mt < 2; mt++)
                ap[mt] = *(const bf16x8*)&ps[w][(mt * 16 + cl) * P_PITCH + kk * 32 + quad * 8];
#pragma unroll
            for (int dt = 0; dt < 4; dt++) {
                bf16x8 bv8 = *(const bf16x8*)&vbuf[kk * 2048 + (dt * 16 + cl) * 32 + qo];
#pragma unroll
                for (int mt = 0; mt < 2; mt++)
                    O[mt][dt] = __builtin_amdgcn_mfma_f32_16x16x32_bf16(ap[mt], bv8, O[mt][dt], 0, 0, 0);
            }
        }
    }

#pragma unroll
    for (int mt = 0; mt < 2; mt++)
#pragma unroll
        for (int r = 0; r < 4; r++) {
            float s0 = l_r[mt][r];
#pragma unroll
            for (int d = 1; d < 16; d <<= 1) s0 += __shfl_xor(s0, d, 64);
            l_r[mt][r] = s0;
        }

#pragma unroll
    for (int mt = 0; mt < 2; mt++) {
        const long orow0 = qrow0 + mt * 16 + quad * 4;
#pragma unroll
        for (int dt = 0; dt < 4; dt++) {
            int col = h * HEAD_D + dt * 16 + cl;
#pragma unroll
            for (int r = 0; r < 4; r++)
                out[(orow0 + r) * HDIM + col] = O[mt][dt][r] / l_r[mt][r];
        }
    }
}

// ---------------- launch ----------------------------------------------------
extern "C" void kernel_launch(void* const* d_in, const int* in_sizes, int n_in,
                              void* d_out, int out_size, void* d_ws, size_t ws_size,
                              hipStream_t stream) {
    const float* hidden = (const float*)d_in[0];
    const float* mask   = (const float*)d_in[1];
    const int*   remain = (const int*)d_in[2];
    const float* Wq = (const float*)d_in[3];
    const float* bq = (const float*)d_in[4];
    const float* Wk = (const float*)d_in[5];
    const float* bk = (const float*)d_in[6];
    const float* Wv = (const float*)d_in[7];
    const float* bv = (const float*)d_in[8];
    float* out = (float*)d_out;

    // ws (~65MB): pos 16K | valid 16K | hbf 16.78M | wkvq 6.29M (Wk|Wv|Wq
    // contiguous!) | qp 8.39M | kp 16.78M | vt 16.78M
    char* ws = (char*)d_ws;
    size_t off = 0;
    short* pos   = (short*)(ws + off); off += 16384;
    int* valid = (int*)(ws + off); off += 16384;
    ushort_t* hbf  = (ushort_t*)(ws + off); off += (size_t)BATCH * S_LEN * HDIM * 2;
    ushort_t* wkvq = (ushort_t*)(ws + off); off += (size_t)3 * HDIM * HDIM * 2;
    ushort_t* qp  = (ushort_t*)(ws + off); off += (size_t)BATCH * KSEL * HDIM * 2;
    ushort_t* kp  = (ushort_t*)(ws + off); off += (size_t)BATCH * S_LEN * HDIM * 2;
    ushort_t* vt  = (ushort_t*)(ws + off); off += (size_t)BATCH * S_LEN * HDIM * 2;

    prep_kernel<<<2824, 1024, 0, stream>>>(hidden, Wq, Wk, Wv, remain,
                                           hbf, wkvq + 2 * 1048576, wkvq,
                                           wkvq + 1048576, pos, valid);
    gemm8<<<384, 512, 0, stream>>>(hbf, wkvq, bk, bv, bq, pos, valid, kp, vt, qp);
    attn_kernel<<<dim3(4, NHEADS, BATCH), 256, 0, stream>>>(qp, kp, vt, mask, out);
}